// Round 1
// baseline (396.010 us; speedup 1.0000x reference)
//
#include <hip/hip_runtime.h>
#include <math.h>

// ---------------- problem constants ----------------
#define N        2048
#define LOG2N    11
#define NT       256      // threads per block
#define NSC      81       // number of scales (J+1)
#define BATCH    64
#define WS_WIN   94       // sliding window = 32*3-2
#define NOUT     1955     // N - WS_WIN + 1
#define DT_S     0.1f
#define W0_C     6.0f
#define PI_F     3.14159265358979f
#define TWOPI_F  6.28318530717959f
#define PIM14    0.7511255444649425f   // pi^(-1/4)

// ---------------- Stockham radix-2 FFT in LDS ----------------
// sign = -1: forward DFT (numpy fft). sign = +1: inverse exponent (scale 1/N
// must be folded into the spectral filter by the caller).
// Ping-pongs a<->b; with 11 (odd) stages the result lands in `b`; the
// returned pointer is the buffer holding the result.
__device__ __forceinline__ float2* fft_pp(float2* a, float2* b, int tid, float sign) {
    float2* src = a;
    float2* dst = b;
    for (int st = 0; st < LOG2N; ++st) {
        const int   m   = 1 << st;
        const int   l   = (N / 2) >> st;
        const float pil = sign * (PI_F / (float)l);
        __syncthreads();
        #pragma unroll
        for (int qq = 0; qq < (N / 2) / NT; ++qq) {
            int    q  = tid + qq * NT;
            int    j  = q >> st;             // q / m
            float2 c0 = src[q];
            float2 c1 = src[q + N / 2];
            float  ang = pil * (float)j;     // sign * pi * j / l, |ang| < pi
            float  sn, cs;
            __sincosf(ang, &sn, &cs);
            float dx = c0.x - c1.x, dy = c0.y - c1.y;
            int   wb = q + j * m;            // k + 2*j*m
            dst[wb]     = make_float2(c0.x + c1.x, c0.y + c1.y);
            dst[wb + m] = make_float2(cs * dx - sn * dy, cs * dy + sn * dx);
        }
        float2* t = src; src = dst; dst = t;
    }
    __syncthreads();
    return src;
}

// ---------------- K1: normalize + forward FFT of each signal ----------------
// grid = BATCH*2 blocks, one signal per block.
__global__ __launch_bounds__(NT) void k_fft_in(const float* __restrict__ x,
                                               float2* __restrict__ spec) {
    __shared__ float2 bufA[N];
    __shared__ float2 bufB[N];
    __shared__ float  rs[NT], rq[NT];
    const int    tid = threadIdx.x;
    const float* y   = x + (size_t)blockIdx.x * N;

    float v[8];
    float lsum = 0.f, lsq = 0.f;
    #pragma unroll
    for (int i = 0; i < 8; ++i) {
        float t = y[tid + i * NT];
        v[i] = t; lsum += t; lsq += t * t;
    }
    rs[tid] = lsum; rq[tid] = lsq;
    __syncthreads();
    for (int o = NT / 2; o > 0; o >>= 1) {
        if (tid < o) { rs[tid] += rs[tid + o]; rq[tid] += rq[tid + o]; }
        __syncthreads();
    }
    const float mean = rs[0] * (1.f / N);
    const float var  = rq[0] * (1.f / N) - mean * mean;
    const float inv  = rsqrtf(var);   // jnp.std, ddof=0

    #pragma unroll
    for (int i = 0; i < 8; ++i)
        bufA[tid + i * NT] = make_float2((v[i] - mean) * inv, 0.f);

    float2* res = fft_pp(bufA, bufB, tid, -1.f);

    float2* o2 = spec + (size_t)blockIdx.x * N;
    #pragma unroll
    for (int i = 0; i < 8; ++i) o2[tid + i * NT] = res[tid + i * NT];
}

// ---------------- K2: per (batch, scale) CWT + smoothing ----------------
// grid = cb*NSC blocks. Writes float4 (S1, S2, S12.re, S12.im) rows of length N.
__global__ __launch_bounds__(NT) void k_wct(const float2* __restrict__ spec,
                                            float4* __restrict__ T, int b0) {
    __shared__ float2 bufA[N];
    __shared__ float2 bufB[N];
    __shared__ float2 bufC[N];
    const int tid  = threadIdx.x;
    const int sidx = blockIdx.x % NSC;
    const int bl   = blockIdx.x / NSC;
    const int b    = b0 + bl;

    const float s0    = 2.f * DT_S * (W0_C + sqrtf(2.f + W0_C * W0_C)) / (4.f * PI_F);
    const float s     = s0 * exp2f(0.125f * (float)sidx);
    const float inv_s = 1.f / s;

    const float2* yh1 = spec + (size_t)(b * 2 + 0) * N;
    const float2* yh2 = spec + (size_t)(b * 2 + 1) * N;

    // Morlet filter (one-sided, w>0), unit-energy norm, with ifft 1/N folded in
    const float nrm   = PIM14 * sqrtf(TWOPI_F * s / DT_S) * (1.f / N);
    const float wstep = TWOPI_F / ((float)N * DT_S);
    #pragma unroll
    for (int i = 0; i < 8; ++i) {
        int   k = tid + i * NT;
        float f = 0.f;
        if (k >= 1 && k < N / 2) {
            float arg = s * (wstep * (float)k) - W0_C;
            f = nrm * expf(-0.5f * arg * arg);
        }
        float2 a = yh1[k], c = yh2[k];
        bufA[k] = make_float2(a.x * f, a.y * f);
        bufC[k] = make_float2(c.x * f, c.y * f);
    }
    float2* W1 = fft_pp(bufA, bufB, tid, +1.f);   // -> bufB
    float2* W2 = fft_pp(bufC, bufA, tid, +1.f);   // -> bufA

    // products (elementwise, own-index only):
    //   bufC = P1 + i*P2  (packed real pair), bufA = W1*conj(W2)/s
    #pragma unroll
    for (int i = 0; i < 8; ++i) {
        int    k  = tid + i * NT;
        float2 w1 = W1[k], w2 = W2[k];
        bufC[k] = make_float2((w1.x * w1.x + w1.y * w1.y) * inv_s,
                              (w2.x * w2.x + w2.y * w2.y) * inv_s);
        bufA[k] = make_float2((w1.x * w2.x + w1.y * w2.y) * inv_s,
                              (w1.y * w2.x - w1.x * w2.y) * inv_s);
    }

    // Gaussian time-smoothing filter in Fourier domain, ifft 1/N folded in
    const float sdt = s / DT_S;
    const float fc  = -0.5f * sdt * sdt * (TWOPI_F / (float)N) * (TWOPI_F / (float)N);

    // smooth packed powers: fft -> filter -> ifft
    float2* Pf = fft_pp(bufC, bufB, tid, -1.f);   // -> bufB
    #pragma unroll
    for (int i = 0; i < 8; ++i) {
        int   k  = tid + i * NT;
        int   mk = min(k, N - k);
        float F  = expf(fc * (float)(mk * mk)) * (1.f / N);
        Pf[k].x *= F; Pf[k].y *= F;
    }
    float2* Psm = fft_pp(bufB, bufC, tid, +1.f);  // -> bufC

    // smooth cross term
    float2* Cf = fft_pp(bufA, bufB, tid, -1.f);   // -> bufB
    #pragma unroll
    for (int i = 0; i < 8; ++i) {
        int   k  = tid + i * NT;
        int   mk = min(k, N - k);
        float F  = expf(fc * (float)(mk * mk)) * (1.f / N);
        Cf[k].x *= F; Cf[k].y *= F;
    }
    float2* Csm = fft_pp(bufB, bufA, tid, +1.f);  // -> bufA

    float4* To = T + ((size_t)bl * NSC + sidx) * N;
    #pragma unroll
    for (int i = 0; i < 8; ++i) {
        int k = tid + i * NT;
        To[k] = make_float4(Psm[k].x, Psm[k].y, Csm[k].x, Csm[k].y);
    }
}

// ---------------- K3: scale-axis boxcar conv + coherence + scale sum --------
// grid = cb*8 blocks; thread <-> one time index t.
__global__ __launch_bounds__(NT) void k_coh(const float4* __restrict__ T,
                                            float* __restrict__ coh, int b0) {
    const int bl = blockIdx.x >> 3;
    const int t  = ((blockIdx.x & 7) << 8) + threadIdx.x;
    const int b  = b0 + bl;
    const float4* col = T + (size_t)bl * NSC * N + t;

    float4 q[10];
    #pragma unroll
    for (int i = 0; i < 10; ++i) q[i] = make_float4(0.f, 0.f, 0.f, 0.f);
    #pragma unroll
    for (int i = 0; i < 5; ++i) q[5 + i] = col[(size_t)i * N];

    float acc = 0.f;
    const float w9 = 1.f / 9.f;
    for (int i = 0; i < NSC; ++i) {
        float sx = 0.f, sy = 0.f, sz = 0.f, sw = 0.f;
        #pragma unroll
        for (int k = 0; k < 10; ++k) { sx += q[k].x; sy += q[k].y; sz += q[k].z; sw += q[k].w; }
        float s1 = (sx - 0.5f * (q[0].x + q[9].x)) * w9;
        float s2 = (sy - 0.5f * (q[0].y + q[9].y)) * w9;
        float sr = (sz - 0.5f * (q[0].z + q[9].z)) * w9;
        float si = (sw - 0.5f * (q[0].w + q[9].w)) * w9;
        acc += (sr * sr + si * si) / (s1 * s2);
        #pragma unroll
        for (int k = 0; k < 9; ++k) q[k] = q[k + 1];
        int c = i + 5;
        q[9] = (c < NSC) ? col[(size_t)c * N] : make_float4(0.f, 0.f, 0.f, 0.f);
    }
    coh[(size_t)b * N + t] = acc;
}

// ---------------- K4: sliding-window sum over time ----------------
__global__ __launch_bounds__(NT) void k_win(const float* __restrict__ coh,
                                            float* __restrict__ out) {
    __shared__ float row[N];
    const int b   = blockIdx.x;
    const int tid = threadIdx.x;
    for (int i = tid; i < N; i += NT) row[i] = coh[(size_t)b * N + i];
    __syncthreads();
    for (int t0 = tid; t0 < NOUT; t0 += NT) {
        float ssum = 0.f;
        for (int k = 0; k < WS_WIN; ++k) ssum += row[t0 + k];
        out[(size_t)b * NOUT + t0] = ssum;
    }
}

// ---------------- host launcher ----------------
extern "C" void kernel_launch(void* const* d_in, const int* in_sizes, int n_in,
                              void* d_out, int out_size, void* d_ws, size_t ws_size,
                              hipStream_t stream) {
    const float* x   = (const float*)d_in[0];
    float*       out = (float*)d_out;
    char*        ws  = (char*)d_ws;

    const size_t spec_bytes = (size_t)BATCH * 2 * N * sizeof(float2); // 2 MB
    const size_t coh_bytes  = (size_t)BATCH * N * sizeof(float);      // 512 KB
    const size_t perBatchT  = (size_t)NSC * N * sizeof(float4);       // ~2.65 MB

    float2* spec = (float2*)ws;
    float*  coh  = (float*)(ws + spec_bytes);
    float4* T    = (float4*)(ws + spec_bytes + coh_bytes);

    size_t avail = (ws_size > spec_bytes + coh_bytes) ? (ws_size - spec_bytes - coh_bytes) : 0;
    int chunk = (int)(avail / perBatchT);
    if (chunk < 1) chunk = 1;
    if (chunk > BATCH) chunk = BATCH;

    k_fft_in<<<BATCH * 2, NT, 0, stream>>>(x, spec);
    for (int b0 = 0; b0 < BATCH; b0 += chunk) {
        int cb = BATCH - b0 < chunk ? BATCH - b0 : chunk;
        k_wct<<<cb * NSC, NT, 0, stream>>>(spec, T, b0);
        k_coh<<<cb * 8, NT, 0, stream>>>(T, coh, b0);
    }
    k_win<<<BATCH, NT, 0, stream>>>(coh, out);
}

// Round 2
// 211.622 us; speedup vs baseline: 1.8713x; 1.8713x over previous
//
#include <hip/hip_runtime.h>
#include <math.h>

// ---------------- problem constants ----------------
#define N        2048
#define NT       256      // threads per block
#define NSC      81       // number of scales (J+1)
#define BATCH    64
#define WS_WIN   94       // sliding window = 32*3-2
#define NOUT     1955     // N - WS_WIN + 1
#define DT_S     0.1f
#define W0_C     6.0f
#define PI_F     3.14159265358979f
#define TWOPI_F  6.28318530717959f
#define PIM14    0.7511255444649425f   // pi^(-1/4)
#define C_SQ2H   0.70710678118654752f  // sqrt(2)/2

// pad-swizzle: +1 element every 16 -> all stage read/write patterns hit the
// b64 bandwidth floor (no bank conflicts beyond the 4-lane minimum)
#define SWZ(e)   ((e) + ((e) >> 4))
#define LDSN     2176     // 2048 + 128 pad elements

__device__ __forceinline__ float2 cadd2(float2 a, float2 b) { return make_float2(a.x + b.x, a.y + b.y); }
__device__ __forceinline__ float2 csub2(float2 a, float2 b) { return make_float2(a.x - b.x, a.y - b.y); }
__device__ __forceinline__ float2 cmul2(float2 a, float2 b) { return make_float2(a.x * b.x - a.y * b.y, a.x * b.y + a.y * b.x); }

// ---------------- mixed-radix Stockham (DIT recombination), radices 8,8,8,4 -
// Verified index/twiddle scheme: stage radix r, m = product of done radices,
// q in [0,N/r), j=q/m, k=q%m; reads src[q + p*N/r]; r-point DFT (sign s);
// output u twiddled by e^{s*2pi*i*j*u*m/N}; write dst[j*r*m + u*m + k].
template<int SGN>
__device__ __forceinline__ void stage8(const float2* __restrict__ src,
                                       float2* __restrict__ dst,
                                       int q, int shift) {
    const float s = (float)SGN;
    float2 x0 = src[SWZ(q)];
    float2 x1 = src[SWZ(q + 256)];
    float2 x2 = src[SWZ(q + 512)];
    float2 x3 = src[SWZ(q + 768)];
    float2 x4 = src[SWZ(q + 1024)];
    float2 x5 = src[SWZ(q + 1280)];
    float2 x6 = src[SWZ(q + 1536)];
    float2 x7 = src[SWZ(q + 1792)];

    const int m  = 1 << shift;
    const int jm = q & ~(m - 1);          // j*m

    // 8-point DFT, natural-order outputs y0..y7
    float2 t0 = cadd2(x0, x4), t1 = cadd2(x1, x5), t2 = cadd2(x2, x6), t3 = cadd2(x3, x7);
    float2 u0 = csub2(x0, x4);
    float2 d1 = csub2(x1, x5);
    float2 d2 = csub2(x2, x6);
    float2 d3 = csub2(x3, x7);
    float2 u1 = make_float2(C_SQ2H * (d1.x - s * d1.y), C_SQ2H * (d1.y + s * d1.x));   // * w8^1
    float2 u2 = make_float2(-s * d2.y, s * d2.x);                                      // * (s i)
    float2 u3 = make_float2(-C_SQ2H * (d3.x + s * d3.y), C_SQ2H * (s * d3.x - d3.y));  // * w8^3

    float2 a0 = cadd2(t0, t2), a1 = cadd2(t1, t3), b0 = csub2(t0, t2), e1 = csub2(t1, t3);
    float2 b1 = make_float2(-s * e1.y, s * e1.x);
    float2 y0 = cadd2(a0, a1), y4 = csub2(a0, a1), y2 = cadd2(b0, b1), y6 = csub2(b0, b1);

    float2 c0 = cadd2(u0, u2), c1 = cadd2(u1, u3), g0 = csub2(u0, u2), h1 = csub2(u1, u3);
    float2 g1 = make_float2(-s * h1.y, s * h1.x);
    float2 y1 = cadd2(c0, c1), y5 = csub2(c0, c1), y3 = cadd2(g0, g1), y7 = csub2(g0, g1);

    // twiddles w^u, w = exp(s*2pi*i*jm/N); powers via cmul chain
    float ang = s * (TWOPI_F / (float)N) * (float)jm;
    float sn, cs; __sincosf(ang, &sn, &cs);
    float2 w1 = make_float2(cs, sn);
    float2 w2 = cmul2(w1, w1);
    float2 w3 = cmul2(w2, w1);
    float2 w4 = cmul2(w2, w2);
    float2 w5 = cmul2(w3, w2);
    float2 w6 = cmul2(w3, w3);
    float2 w7 = cmul2(w4, w3);

    const int base = q + 7 * jm;          // j*8m + k
    dst[SWZ(base)]         = y0;
    dst[SWZ(base + m)]     = cmul2(y1, w1);
    dst[SWZ(base + 2 * m)] = cmul2(y2, w2);
    dst[SWZ(base + 3 * m)] = cmul2(y3, w3);
    dst[SWZ(base + 4 * m)] = cmul2(y4, w4);
    dst[SWZ(base + 5 * m)] = cmul2(y5, w5);
    dst[SWZ(base + 6 * m)] = cmul2(y6, w6);
    dst[SWZ(base + 7 * m)] = cmul2(y7, w7);
}

// final radix-4 stage: m=512, l=1 -> j=0, no twiddles; 2 q's per thread
template<int SGN>
__device__ __forceinline__ void stage4f(const float2* __restrict__ src,
                                        float2* __restrict__ dst, int tid) {
    const float s = (float)SGN;
    #pragma unroll
    for (int qq = 0; qq < 2; ++qq) {
        int q = tid + qq * NT;
        float2 x0 = src[SWZ(q)];
        float2 x1 = src[SWZ(q + 512)];
        float2 x2 = src[SWZ(q + 1024)];
        float2 x3 = src[SWZ(q + 1536)];
        float2 a0 = cadd2(x0, x2), a1 = cadd2(x1, x3);
        float2 b0 = csub2(x0, x2), e1 = csub2(x1, x3);
        float2 b1 = make_float2(-s * e1.y, s * e1.x);
        dst[SWZ(q)]        = cadd2(a0, a1);
        dst[SWZ(q + 512)]  = cadd2(b0, b1);
        dst[SWZ(q + 1024)] = csub2(a0, a1);
        dst[SWZ(q + 1536)] = csub2(b0, b1);
    }
}

// full 2048-point FFT; input in `a` at thread-owned indices (tid + i*NT),
// result lands back in `a` at thread-owned indices. `b` is scratch.
// SGN=-1: forward (numpy fft). SGN=+1: inverse exponent (1/N not applied).
template<int SGN>
__device__ __forceinline__ void fft2048(float2* a, float2* b, int tid) {
    __syncthreads();                 // protect b reuse from previous FFT
    stage8<SGN>(a, b, tid, 0);       // m=1
    __syncthreads();
    stage8<SGN>(b, a, tid, 3);       // m=8
    __syncthreads();
    stage8<SGN>(a, b, tid, 6);       // m=64
    __syncthreads();
    stage4f<SGN>(b, a, tid);         // m=512 -> result in a, thread-owned idx
}

// ---------------- K1: normalize + forward FFT of each signal ----------------
__global__ __launch_bounds__(NT) void k_fft_in(const float* __restrict__ x,
                                               float2* __restrict__ spec) {
    __shared__ float2 bufA[LDSN];
    __shared__ float2 bufB[LDSN];
    __shared__ float  rs[NT], rq[NT];
    const int    tid = threadIdx.x;
    const float* y   = x + (size_t)blockIdx.x * N;

    float v[8];
    float lsum = 0.f, lsq = 0.f;
    #pragma unroll
    for (int i = 0; i < 8; ++i) {
        float t = y[tid + i * NT];
        v[i] = t; lsum += t; lsq += t * t;
    }
    rs[tid] = lsum; rq[tid] = lsq;
    __syncthreads();
    for (int o = NT / 2; o > 0; o >>= 1) {
        if (tid < o) { rs[tid] += rs[tid + o]; rq[tid] += rq[tid + o]; }
        __syncthreads();
    }
    const float mean = rs[0] * (1.f / N);
    const float var  = rq[0] * (1.f / N) - mean * mean;
    const float inv  = rsqrtf(var);

    #pragma unroll
    for (int i = 0; i < 8; ++i)
        bufA[SWZ(tid + i * NT)] = make_float2((v[i] - mean) * inv, 0.f);

    fft2048<-1>(bufA, bufB, tid);

    float2* o2 = spec + (size_t)blockIdx.x * N;
    #pragma unroll
    for (int i = 0; i < 8; ++i) o2[tid + i * NT] = bufA[SWZ(tid + i * NT)];
}

// ---------------- K2: per (batch, scale) CWT + smoothing ----------------
__global__ __launch_bounds__(NT) void k_wct(const float2* __restrict__ spec,
                                            float4* __restrict__ T, int b0) {
    __shared__ float2 bufA[LDSN];
    __shared__ float2 bufB[LDSN];
    __shared__ float2 bufC[LDSN];
    const int tid  = threadIdx.x;
    const int sidx = blockIdx.x % NSC;
    const int bl   = blockIdx.x / NSC;
    const int b    = b0 + bl;

    const float s0    = 2.f * DT_S * (W0_C + sqrtf(2.f + W0_C * W0_C)) / (4.f * PI_F);
    const float s     = s0 * exp2f(0.125f * (float)sidx);
    const float inv_s = 1.f / s;

    const float2* yh1 = spec + (size_t)(b * 2 + 0) * N;
    const float2* yh2 = spec + (size_t)(b * 2 + 1) * N;

    // Morlet filter (w>0 one-sided), unit-energy norm, ifft 1/N folded in
    const float nrm   = PIM14 * sqrtf(TWOPI_F * s / DT_S) * (1.f / N);
    const float wstep = TWOPI_F / ((float)N * DT_S);
    #pragma unroll
    for (int i = 0; i < 8; ++i) {
        int   k = tid + i * NT;
        float f = 0.f;
        if (k >= 1 && k < N / 2) {
            float arg = s * (wstep * (float)k) - W0_C;
            f = nrm * expf(-0.5f * arg * arg);
        }
        float2 a = yh1[k], c = yh2[k];
        bufA[SWZ(k)] = make_float2(a.x * f, a.y * f);
        bufC[SWZ(k)] = make_float2(c.x * f, c.y * f);
    }
    fft2048<+1>(bufA, bufB, tid);   // W1 -> bufA (thread-owned idx)
    fft2048<+1>(bufC, bufB, tid);   // W2 -> bufC

    // pointwise products (thread-owned indices, no barrier needed):
    // bufA <- P1 + i*P2 (packed powers), bufC <- W1*conj(W2)/s
    #pragma unroll
    for (int i = 0; i < 8; ++i) {
        int    k  = tid + i * NT;
        float2 w1 = bufA[SWZ(k)], w2 = bufC[SWZ(k)];
        bufA[SWZ(k)] = make_float2((w1.x * w1.x + w1.y * w1.y) * inv_s,
                                   (w2.x * w2.x + w2.y * w2.y) * inv_s);
        bufC[SWZ(k)] = make_float2((w1.x * w2.x + w1.y * w2.y) * inv_s,
                                   (w1.y * w2.x - w1.x * w2.y) * inv_s);
    }

    // Gaussian time-smoothing in Fourier domain (1/N folded into F)
    const float sdt = s / DT_S;
    const float fc  = -0.5f * sdt * sdt * (TWOPI_F / (float)N) * (TWOPI_F / (float)N);

    fft2048<-1>(bufA, bufB, tid);
    #pragma unroll
    for (int i = 0; i < 8; ++i) {
        int   k  = tid + i * NT;
        int   mk = min(k, N - k);
        float F  = expf(fc * (float)(mk * mk)) * (1.f / N);
        bufA[SWZ(k)].x *= F; bufA[SWZ(k)].y *= F;
    }
    fft2048<+1>(bufA, bufB, tid);   // Psm -> bufA

    fft2048<-1>(bufC, bufB, tid);
    #pragma unroll
    for (int i = 0; i < 8; ++i) {
        int   k  = tid + i * NT;
        int   mk = min(k, N - k);
        float F  = expf(fc * (float)(mk * mk)) * (1.f / N);
        bufC[SWZ(k)].x *= F; bufC[SWZ(k)].y *= F;
    }
    fft2048<+1>(bufC, bufB, tid);   // Csm -> bufC

    float4* To = T + ((size_t)bl * NSC + sidx) * N;
    #pragma unroll
    for (int i = 0; i < 8; ++i) {
        int k = tid + i * NT;
        float2 p = bufA[SWZ(k)], c = bufC[SWZ(k)];
        To[k] = make_float4(p.x, p.y, c.x, c.y);
    }
}

// ---------------- K3: scale-axis boxcar conv + coherence + scale sum --------
__global__ __launch_bounds__(NT) void k_coh(const float4* __restrict__ T,
                                            float* __restrict__ coh, int b0) {
    const int bl = blockIdx.x >> 3;
    const int t  = ((blockIdx.x & 7) << 8) + threadIdx.x;
    const int b  = b0 + bl;
    const float4* col = T + (size_t)bl * NSC * N + t;

    float4 q[10];
    #pragma unroll
    for (int i = 0; i < 10; ++i) q[i] = make_float4(0.f, 0.f, 0.f, 0.f);
    #pragma unroll
    for (int i = 0; i < 5; ++i) q[5 + i] = col[(size_t)i * N];

    float acc = 0.f;
    const float w9 = 1.f / 9.f;
    for (int i = 0; i < NSC; ++i) {
        float sx = 0.f, sy = 0.f, sz = 0.f, sw = 0.f;
        #pragma unroll
        for (int k = 0; k < 10; ++k) { sx += q[k].x; sy += q[k].y; sz += q[k].z; sw += q[k].w; }
        float s1 = (sx - 0.5f * (q[0].x + q[9].x)) * w9;
        float s2 = (sy - 0.5f * (q[0].y + q[9].y)) * w9;
        float sr = (sz - 0.5f * (q[0].z + q[9].z)) * w9;
        float si = (sw - 0.5f * (q[0].w + q[9].w)) * w9;
        acc += (sr * sr + si * si) / (s1 * s2);
        #pragma unroll
        for (int k = 0; k < 9; ++k) q[k] = q[k + 1];
        int c = i + 5;
        q[9] = (c < NSC) ? col[(size_t)c * N] : make_float4(0.f, 0.f, 0.f, 0.f);
    }
    coh[(size_t)b * N + t] = acc;
}

// ---------------- K4: sliding-window sum over time ----------------
__global__ __launch_bounds__(NT) void k_win(const float* __restrict__ coh,
                                            float* __restrict__ out) {
    __shared__ float row[N];
    const int b   = blockIdx.x;
    const int tid = threadIdx.x;
    for (int i = tid; i < N; i += NT) row[i] = coh[(size_t)b * N + i];
    __syncthreads();
    for (int t0 = tid; t0 < NOUT; t0 += NT) {
        float ssum = 0.f;
        for (int k = 0; k < WS_WIN; ++k) ssum += row[t0 + k];
        out[(size_t)b * NOUT + t0] = ssum;
    }
}

// ---------------- host launcher ----------------
extern "C" void kernel_launch(void* const* d_in, const int* in_sizes, int n_in,
                              void* d_out, int out_size, void* d_ws, size_t ws_size,
                              hipStream_t stream) {
    const float* x   = (const float*)d_in[0];
    float*       out = (float*)d_out;
    char*        ws  = (char*)d_ws;

    const size_t spec_bytes = (size_t)BATCH * 2 * N * sizeof(float2); // 2 MB
    const size_t coh_bytes  = (size_t)BATCH * N * sizeof(float);      // 512 KB
    const size_t perBatchT  = (size_t)NSC * N * sizeof(float4);       // ~2.65 MB

    float2* spec = (float2*)ws;
    float*  coh  = (float*)(ws + spec_bytes);
    float4* T    = (float4*)(ws + spec_bytes + coh_bytes);

    size_t avail = (ws_size > spec_bytes + coh_bytes) ? (ws_size - spec_bytes - coh_bytes) : 0;
    int chunk = (int)(avail / perBatchT);
    if (chunk < 1) chunk = 1;
    if (chunk > BATCH) chunk = BATCH;

    k_fft_in<<<BATCH * 2, NT, 0, stream>>>(x, spec);
    for (int b0 = 0; b0 < BATCH; b0 += chunk) {
        int cb = BATCH - b0 < chunk ? BATCH - b0 : chunk;
        k_wct<<<cb * NSC, NT, 0, stream>>>(spec, T, b0);
        k_coh<<<cb * 8, NT, 0, stream>>>(T, coh, b0);
    }
    k_win<<<BATCH, NT, 0, stream>>>(coh, out);
}